// Round 13
// baseline (163.555 us; speedup 1.0000x reference)
//
#include <hip/hip_runtime.h>
#include <hip/hip_bf16.h>

__device__ __forceinline__ float bf2f(unsigned short u) {
    union { unsigned int i; float f; } v; v.i = ((unsigned int)u) << 16; return v.f;
}
__device__ __forceinline__ unsigned short f2bf(float f) {
    __hip_bfloat16 h = __float2bfloat16(f);
    return *reinterpret_cast<unsigned short*>(&h);
}

// ws layout:
//   Q    fp32 [b][g][4096][16]                    4 MB
//   K    bf16 canvas [b][g][80][80][16]           3.2768 MB (zero-padded)
//   V    bf16 canvas [b][g][80][80][16]           3.2768 MB
//   ACC  fp32 [p][b][128][4096]  p=0..4           20 MB   raw softmax partials
//   Mb   fp32 [p][b][8][4096]                     1.31 MB chunk max
//   Db   fp32 [p][b][8][4096]                     1.31 MB chunk denom
// v10 = round-9 v6 champion byte-for-byte, ONE change: attn gets
// __launch_bounds__(256, 4) -> VGPR capped at 128 (was 136, just over the
// 128 occupancy step) -> 4 waves/SIMD instead of 3 for the latency-bound
// attn. No algorithm change.

#define CANVAS_SLAB 102400   // 80*80*16 ushorts per (b,g)

__global__ __launch_bounds__(256) void pad_zero_kernel(uint4* __restrict__ p)
{
    const size_t i = (size_t)blockIdx.x * 256 + threadIdx.x;
    p[i] = make_uint4(0u, 0u, 0u, 0u);   // grid sized exactly: 1600 * 256
}

// ---------------------------------------------------------------------------
// conv v2 (unchanged): three 1x1 convs, fp32, register-tiled GEMM.
// ---------------------------------------------------------------------------
__global__ __launch_bounds__(256) void conv_kernel(
    const float* __restrict__ fm,
    const float* __restrict__ wq, const float* __restrict__ wk,
    const float* __restrict__ wv,
    float* __restrict__ Qout,
    unsigned short* __restrict__ K0,
    unsigned short* __restrict__ V0)
{
    const int sel = blockIdx.z;
    const int by  = blockIdx.y;
    const float* W = (sel == 0) ? wq : ((sel == 1) ? wk : wv);
    const int c0 = (sel == 0) ? 128 : 0;

    __shared__ float w_s[64 * 68];
    __shared__ float x_s[64 * 68];

    const int tid = threadIdx.x;
    const int P0  = blockIdx.x * 64;
    const int b   = P0 >> 12;
    const int hw0 = P0 & 4095;

    float acc[4][4];
    #pragma unroll
    for (int i = 0; i < 4; ++i)
        #pragma unroll
        for (int j = 0; j < 4; ++j) acc[i][j] = 0.f;

    const int ocb = (tid >> 4) * 4;
    const int pxb = (tid & 15) * 4;

    for (int kh = 0; kh < 128; kh += 64) {
        {
            const int o    = tid >> 2;
            const int koff = (tid & 3) * 16;
            #pragma unroll
            for (int i = 0; i < 4; ++i) {
                float4 v = *(const float4*)(W + (size_t)(by * 64 + o) * 128 + kh + koff + i * 4);
                w_s[(koff + i * 4 + 0) * 68 + o] = v.x;
                w_s[(koff + i * 4 + 1) * 68 + o] = v.y;
                w_s[(koff + i * 4 + 2) * 68 + o] = v.z;
                w_s[(koff + i * 4 + 3) * 68 + o] = v.w;
            }
        }
        {
            const int c  = tid >> 2;
            const int pc = (tid & 3) * 16;
            const float* src = fm + (((size_t)(b * 256 + c0 + kh + c)) << 12) + hw0 + pc;
            #pragma unroll
            for (int i = 0; i < 4; ++i)
                *(float4*)(&x_s[c * 68 + pc + i * 4]) = *(const float4*)(src + i * 4);
        }
        __syncthreads();
        #pragma unroll 8
        for (int k = 0; k < 64; ++k) {
            float4 wa = *(const float4*)(&w_s[k * 68 + ocb]);
            float4 xv = *(const float4*)(&x_s[k * 68 + pxb]);
            const float wf[4] = {wa.x, wa.y, wa.z, wa.w};
            const float xf[4] = {xv.x, xv.y, xv.z, xv.w};
            #pragma unroll
            for (int i = 0; i < 4; ++i)
                #pragma unroll
                for (int j = 0; j < 4; ++j) acc[i][j] += wf[i] * xf[j];
        }
        __syncthreads();
    }

    const int oc  = by * 64 + ocb;
    const int g   = oc >> 4;
    const int lci = oc & 15;
    const int hh  = hw0 >> 6;
    #pragma unroll
    for (int pj = 0; pj < 4; ++pj) {
        const int ww = pxb + pj;
        if (sel == 0) {
            const size_t base = ((((size_t)(b * 8 + g)) << 12) + (hh * 64 + ww)) * 16 + lci;
            *(float4*)(Qout + base) = make_float4(acc[0][pj], acc[1][pj], acc[2][pj], acc[3][pj]);
        } else {
            const size_t cbase = (size_t)(b * 8 + g) * CANVAS_SLAB
                               + ((size_t)((hh + 8) * 80 + (ww + 8))) * 16 + lci;
            unsigned short tmp[4];
            #pragma unroll
            for (int i = 0; i < 4; ++i) tmp[i] = f2bf(acc[i][pj]);
            unsigned short* dst = ((sel == 1) ? K0 : V0) + cbase;
            *(uint2*)dst = *(const uint2*)tmp;
        }
    }
}

// ---------------------------------------------------------------------------
// attn v10: v6 body (balanced 5-way split, raw partials), serial-chain dotq,
// __launch_bounds__(256,4) for the 128-VGPR occupancy step.
// One thread per (b,g,h,w,part). grid (16, 8, 10), z = part*2 + b.
// ---------------------------------------------------------------------------
struct KV16 { uint4 a, b; };
__device__ __forceinline__ KV16 ld16(const unsigned short* p) {
    KV16 r; r.a = *(const uint4*)p; r.b = *(const uint4*)(p + 8); return r;
}
__device__ __forceinline__ float dotq(const float* q, const KV16& k) {
    const unsigned short* u = (const unsigned short*)&k;
    float s = 0.f;
    #pragma unroll
    for (int c = 0; c < 16; ++c) s += q[c] * bf2f(u[c]);
    return s;
}
__device__ __forceinline__ void axpyq(float* acc, float wgt, const KV16& v) {
    const unsigned short* u = (const unsigned short*)&v;
    #pragma unroll
    for (int c = 0; c < 16; ++c) acc[c] += wgt * bf2f(u[c]);
}

#define CIDX(y, x) (((size_t)(((y) + 8) * 80 + ((x) + 8))) << 4)

// Main-window row-chunk [I0, I0+NI): raw partial (m, den, acc un-normalized).
template<int I0, int NI>
__device__ __forceinline__ void main_chunk(
    const float* qr, const unsigned short* Kp, const unsigned short* Vp,
    const float* __restrict__ rel_h, const float* __restrict__ rel_w,
    int g, int h, int w, float* acc, float& mx, float& den)
{
    float qrel[7];
    const float* rel = (g < 4) ? (rel_h + g * 112) : (rel_w + (g - 4) * 112);
    #pragma unroll
    for (int t = 0; t < 7; ++t) {
        float s = 0.f;
        #pragma unroll
        for (int ci = 0; ci < 16; ++ci) s += qr[ci] * rel[ci * 7 + t];
        qrel[t] = s;
    }
    const bool bias_i = (g < 4);

    float sc[NI * 7];
    mx = -3.4e38f;
    #pragma unroll
    for (int i = 0; i < NI; ++i) {
        const int y = h + (I0 + i) - 3;
        #pragma unroll
        for (int j = 0; j < 7; ++j) {
            const int x = w + j - 3;
            float d = dotq(qr, ld16(Kp + CIDX(y, x)));
            d += bias_i ? qrel[I0 + i] : qrel[j];
            sc[i * 7 + j] = d;
            mx = fmaxf(mx, d);
        }
    }
    den = 0.f;
    #pragma unroll
    for (int k = 0; k < NI * 7; ++k) { sc[k] = __expf(sc[k] - mx); den += sc[k]; }
    #pragma unroll
    for (int i = 0; i < NI; ++i) {
        const int y = h + (I0 + i) - 3;
        #pragma unroll
        for (int j = 0; j < 7; ++j) {
            const int x = w + j - 3;
            axpyq(acc, sc[i * 7 + j], ld16(Vp + CIDX(y, x)));
        }
    }
}

__global__ __launch_bounds__(256, 4) void attn_kernel(
    const float* __restrict__ Q,
    const unsigned short* __restrict__ K0,
    const unsigned short* __restrict__ V0,
    const float* __restrict__ rel_h,
    const float* __restrict__ rel_w,
    float* __restrict__ ACC,
    float* __restrict__ Mb,
    float* __restrict__ Db)
{
    const int tid = threadIdx.x;
    const int w   = tid & 63;
    const int h   = blockIdx.x * 4 + (tid >> 6);
    const int g   = blockIdx.y;
    const int z   = blockIdx.z;       // 0..9
    const int pz  = z >> 1;           // part 0..4 (heavy chunk first)
    const int b   = z & 1;

    const size_t slabQ = ((size_t)(b * 8 + g)) << 16;
    const float* qptr = Q + slabQ + (size_t)(h * 64 + w) * 16;

    float qr[16];
    #pragma unroll
    for (int ci = 0; ci < 16; ++ci) qr[ci] = qptr[ci];

    const unsigned short* Kp = K0 + (size_t)(b * 8 + g) * CANVAS_SLAB;
    const unsigned short* Vp = V0 + (size_t)(b * 8 + g) * CANVAS_SLAB;

    float acc[16];
    #pragma unroll
    for (int ci = 0; ci < 16; ++ci) acc[ci] = 0.f;
    float mx, den;

    if (pz == 0) {
        main_chunk<4, 3>(qr, Kp, Vp, rel_h, rel_w, g, h, w, acc, mx, den);
    } else if (pz == 1) {
        main_chunk<0, 2>(qr, Kp, Vp, rel_h, rel_w, g, h, w, acc, mx, den);
    } else if (pz == 2) {
        main_chunk<2, 2>(qr, Kp, Vp, rel_h, rel_w, g, h, w, acc, mx, den);
    } else if (pz == 3) {
        // refine row (w offsets), raw partial
        float sc[15];
        mx = -3.4e38f;
        #pragma unroll
        for (int j = 0; j < 15; ++j) {
            const int x = w + j - 7;
            const float d = dotq(qr, ld16(Kp + CIDX(h, x)));
            sc[j] = d; mx = fmaxf(mx, d);
        }
        den = 0.f;
        #pragma unroll
        for (int j = 0; j < 15; ++j) { sc[j] = __expf(sc[j] - mx); den += sc[j]; }
        #pragma unroll
        for (int j = 0; j < 15; ++j) {
            const int x = w + j - 7;
            axpyq(acc, sc[j], ld16(Vp + CIDX(h, x)));
        }
    } else {
        // refine col (h offsets), raw partial
        float sc[15];
        mx = -3.4e38f;
        #pragma unroll
        for (int i = 0; i < 15; ++i) {
            const int y = h + i - 7;
            const float d = dotq(qr, ld16(Kp + CIDX(y, w)));
            sc[i] = d; mx = fmaxf(mx, d);
        }
        den = 0.f;
        #pragma unroll
        for (int i = 0; i < 15; ++i) { sc[i] = __expf(sc[i] - mx); den += sc[i]; }
        #pragma unroll
        for (int i = 0; i < 15; ++i) {
            const int y = h + i - 7;
            axpyq(acc, sc[i], ld16(Vp + CIDX(y, w)));
        }
    }

    // store raw partials
    const int hw = h * 64 + w;
    float* op = ACC + ((((size_t)(pz * 2 + b)) * 128 + g * 16) << 12) + hw;
    #pragma unroll
    for (int ci = 0; ci < 16; ++ci)
        op[(size_t)ci << 12] = acc[ci];
    const size_t md = ((((size_t)(pz * 2 + b)) * 8 + g) << 12) + hw;
    Mb[md] = mx;
    Db[md] = den;
}
#undef CIDX

// ---------------------------------------------------------------------------
// combine: out = merge(p0,p1,p2) + p3/d3 + p4/d4.  (unchanged)
// ---------------------------------------------------------------------------
__global__ __launch_bounds__(256) void combine_kernel(
    const float4* __restrict__ ACC,
    const float* __restrict__ Mb, const float* __restrict__ Db,
    float4* __restrict__ out)
{
    const int idx = blockIdx.x * 256 + threadIdx.x;     // 0..262143
    const int i4  = idx & 1023;
    const int ch  = (idx >> 10) & 127;
    const int b   = idx >> 17;
    const int g   = ch >> 4;

    const float4* M4 = (const float4*)Mb;
    const float4* D4 = (const float4*)Db;

    float4 A[5], Mv[3], Dv[5];
    #pragma unroll
    for (int p = 0; p < 5; ++p) {
        A[p]  = ACC[(((size_t)(p * 2 + b) * 128 + ch) << 10) + i4];
        Dv[p] = D4[(((size_t)(p * 2 + b) * 8 + g) << 10) + i4];
    }
    #pragma unroll
    for (int p = 0; p < 3; ++p)
        Mv[p] = M4[(((size_t)(p * 2 + b) * 8 + g) << 10) + i4];

    const float* a0 = (const float*)&A[0]; const float* a1 = (const float*)&A[1];
    const float* a2 = (const float*)&A[2]; const float* a3 = (const float*)&A[3];
    const float* a4 = (const float*)&A[4];
    const float* m0 = (const float*)&Mv[0]; const float* m1 = (const float*)&Mv[1];
    const float* m2 = (const float*)&Mv[2];
    const float* d0 = (const float*)&Dv[0]; const float* d1 = (const float*)&Dv[1];
    const float* d2 = (const float*)&Dv[2]; const float* d3 = (const float*)&Dv[3];
    const float* d4 = (const float*)&Dv[4];

    float res[4];
    #pragma unroll
    for (int c = 0; c < 4; ++c) {
        const float M  = fmaxf(m0[c], fmaxf(m1[c], m2[c]));
        const float e0 = __expf(m0[c] - M);
        const float e1 = __expf(m1[c] - M);
        const float e2 = __expf(m2[c] - M);
        const float num = a0[c] * e0 + a1[c] * e1 + a2[c] * e2;
        const float den = d0[c] * e0 + d1[c] * e1 + d2[c] * e2;
        res[c] = num / den + a3[c] / d3[c] + a4[c] / d4[c];
    }
    out[idx] = make_float4(res[0], res[1], res[2], res[3]);
}

// ---------------------------------------------------------------------------
extern "C" void kernel_launch(void* const* d_in, const int* in_sizes, int n_in,
                              void* d_out, int out_size, void* d_ws, size_t ws_size,
                              hipStream_t stream) {
    (void)in_sizes; (void)n_in; (void)ws_size; (void)out_size;
    const float* fm    = (const float*)d_in[0];
    const float* wq    = (const float*)d_in[1];
    const float* wk    = (const float*)d_in[2];
    const float* wv    = (const float*)d_in[3];
    const float* rel_h = (const float*)d_in[4];
    const float* rel_w = (const float*)d_in[5];

    float* Q = (float*)d_ws;                               // 1048576 f
    unsigned short* K0 = (unsigned short*)(Q + 1048576);   // 1638400 us
    unsigned short* V0 = K0 + 16 * CANVAS_SLAB;            // 1638400 us
    float* ACC = (float*)(V0 + 16 * CANVAS_SLAB);          // 5242880 f
    float* Mb  = ACC + 5242880;                            // 327680 f
    float* Db  = Mb + 327680;                              // 327680 f

    pad_zero_kernel<<<dim3(1600), dim3(256), 0, stream>>>((uint4*)K0);

    conv_kernel<<<dim3(128, 2, 3), dim3(256), 0, stream>>>(
        fm, wq, wk, wv, Q, K0, V0);
    attn_kernel<<<dim3(16, 8, 10), dim3(256), 0, stream>>>(
        Q, K0, V0, rel_h, rel_w, ACC, Mb, Db);
    combine_kernel<<<dim3(1024), dim3(256), 0, stream>>>(
        (const float4*)ACC, Mb, Db, (float4*)d_out);
}

// Round 14
// 105.175 us; speedup vs baseline: 1.5551x; 1.5551x over previous
//
#include <hip/hip_runtime.h>
#include <hip/hip_bf16.h>

__device__ __forceinline__ float bf2f(unsigned short u) {
    union { unsigned int i; float f; } v; v.i = ((unsigned int)u) << 16; return v.f;
}
__device__ __forceinline__ unsigned short f2bf(float f) {
    __hip_bfloat16 h = __float2bfloat16(f);
    return *reinterpret_cast<unsigned short*>(&h);
}

// ws layout:
//   Q    fp32 [b][g][4096][16]                    4 MB
//   K    bf16 canvas [b][g][80][80][16]           3.2768 MB (zero-padded)
//   V    bf16 canvas [b][g][80][80][16]           3.2768 MB
//   ACC  fp32 [p][b][128][4096]  p=0..4           20 MB   raw softmax partials
//   Mb   fp32 [p][b][8][4096]                     1.31 MB chunk max
//   Db   fp32 [p][b][8][4096]                     1.31 MB chunk denom
// CHAMPION (round 9, 104.9 us) restored byte-identical. Parts: p0 = main
// rows 4-6 (21 sc), p1 = rows 0-1 (14), p2 = rows 2-3 (14), p3 = refine row
// (15), p4 = refine col (15). Online-softmax merge of p0..p2 in combine.
// Tested-and-regressed levers (do NOT re-apply): fp32 K/V (+28us, memory-
// bound), per-row online softmax (+10), dot chain-split (+13), LDS staging
// (+9), launch_bounds(256,4) (VGPR->64, 204MB scratch spills, +59).

#define CANVAS_SLAB 102400   // 80*80*16 ushorts per (b,g)

__global__ __launch_bounds__(256) void pad_zero_kernel(uint4* __restrict__ p)
{
    const size_t i = (size_t)blockIdx.x * 256 + threadIdx.x;
    p[i] = make_uint4(0u, 0u, 0u, 0u);   // grid sized exactly: 1600 * 256
}

// ---------------------------------------------------------------------------
// conv v2: three 1x1 convs, fp32, register-tiled GEMM.
// Block = 64 out-ch x 64 px (thread = 4 ch x 4 px), grid (128,2,3) = 768
// blocks = 3/CU. LDS: w_s + x_s 64x68 each.
// ---------------------------------------------------------------------------
__global__ __launch_bounds__(256) void conv_kernel(
    const float* __restrict__ fm,
    const float* __restrict__ wq, const float* __restrict__ wk,
    const float* __restrict__ wv,
    float* __restrict__ Qout,
    unsigned short* __restrict__ K0,
    unsigned short* __restrict__ V0)
{
    const int sel = blockIdx.z;
    const int by  = blockIdx.y;
    const float* W = (sel == 0) ? wq : ((sel == 1) ? wk : wv);
    const int c0 = (sel == 0) ? 128 : 0;

    __shared__ float w_s[64 * 68];
    __shared__ float x_s[64 * 68];

    const int tid = threadIdx.x;
    const int P0  = blockIdx.x * 64;
    const int b   = P0 >> 12;
    const int hw0 = P0 & 4095;

    float acc[4][4];
    #pragma unroll
    for (int i = 0; i < 4; ++i)
        #pragma unroll
        for (int j = 0; j < 4; ++j) acc[i][j] = 0.f;

    const int ocb = (tid >> 4) * 4;
    const int pxb = (tid & 15) * 4;

    for (int kh = 0; kh < 128; kh += 64) {
        {
            const int o    = tid >> 2;
            const int koff = (tid & 3) * 16;
            #pragma unroll
            for (int i = 0; i < 4; ++i) {
                float4 v = *(const float4*)(W + (size_t)(by * 64 + o) * 128 + kh + koff + i * 4);
                w_s[(koff + i * 4 + 0) * 68 + o] = v.x;
                w_s[(koff + i * 4 + 1) * 68 + o] = v.y;
                w_s[(koff + i * 4 + 2) * 68 + o] = v.z;
                w_s[(koff + i * 4 + 3) * 68 + o] = v.w;
            }
        }
        {
            const int c  = tid >> 2;
            const int pc = (tid & 3) * 16;
            const float* src = fm + (((size_t)(b * 256 + c0 + kh + c)) << 12) + hw0 + pc;
            #pragma unroll
            for (int i = 0; i < 4; ++i)
                *(float4*)(&x_s[c * 68 + pc + i * 4]) = *(const float4*)(src + i * 4);
        }
        __syncthreads();
        #pragma unroll 8
        for (int k = 0; k < 64; ++k) {
            float4 wa = *(const float4*)(&w_s[k * 68 + ocb]);
            float4 xv = *(const float4*)(&x_s[k * 68 + pxb]);
            const float wf[4] = {wa.x, wa.y, wa.z, wa.w};
            const float xf[4] = {xv.x, xv.y, xv.z, xv.w};
            #pragma unroll
            for (int i = 0; i < 4; ++i)
                #pragma unroll
                for (int j = 0; j < 4; ++j) acc[i][j] += wf[i] * xf[j];
        }
        __syncthreads();
    }

    const int oc  = by * 64 + ocb;
    const int g   = oc >> 4;
    const int lci = oc & 15;
    const int hh  = hw0 >> 6;
    #pragma unroll
    for (int pj = 0; pj < 4; ++pj) {
        const int ww = pxb + pj;
        if (sel == 0) {
            const size_t base = ((((size_t)(b * 8 + g)) << 12) + (hh * 64 + ww)) * 16 + lci;
            *(float4*)(Qout + base) = make_float4(acc[0][pj], acc[1][pj], acc[2][pj], acc[3][pj]);
        } else {
            const size_t cbase = (size_t)(b * 8 + g) * CANVAS_SLAB
                               + ((size_t)((hh + 8) * 80 + (ww + 8))) * 16 + lci;
            unsigned short tmp[4];
            #pragma unroll
            for (int i = 0; i < 4; ++i) tmp[i] = f2bf(acc[i][pj]);
            unsigned short* dst = ((sel == 1) ? K0 : V0) + cbase;
            *(uint2*)dst = *(const uint2*)tmp;
        }
    }
}

// ---------------------------------------------------------------------------
// attn v6 (champion): balanced 5-way split with raw softmax partials.
// One thread per (b,g,h,w,part). grid (16, 8, 10), z = part*2 + b.
// ---------------------------------------------------------------------------
struct KV16 { uint4 a, b; };
__device__ __forceinline__ KV16 ld16(const unsigned short* p) {
    KV16 r; r.a = *(const uint4*)p; r.b = *(const uint4*)(p + 8); return r;
}
__device__ __forceinline__ float dotq(const float* q, const KV16& k) {
    const unsigned short* u = (const unsigned short*)&k;
    float s = 0.f;
    #pragma unroll
    for (int c = 0; c < 16; ++c) s += q[c] * bf2f(u[c]);
    return s;
}
__device__ __forceinline__ void axpyq(float* acc, float wgt, const KV16& v) {
    const unsigned short* u = (const unsigned short*)&v;
    #pragma unroll
    for (int c = 0; c < 16; ++c) acc[c] += wgt * bf2f(u[c]);
}

#define CIDX(y, x) (((size_t)(((y) + 8) * 80 + ((x) + 8))) << 4)

// Main-window row-chunk [I0, I0+NI): raw partial (m, den, acc un-normalized).
template<int I0, int NI>
__device__ __forceinline__ void main_chunk(
    const float* qr, const unsigned short* Kp, const unsigned short* Vp,
    const float* __restrict__ rel_h, const float* __restrict__ rel_w,
    int g, int h, int w, float* acc, float& mx, float& den)
{
    float qrel[7];
    const float* rel = (g < 4) ? (rel_h + g * 112) : (rel_w + (g - 4) * 112);
    #pragma unroll
    for (int t = 0; t < 7; ++t) {
        float s = 0.f;
        #pragma unroll
        for (int ci = 0; ci < 16; ++ci) s += qr[ci] * rel[ci * 7 + t];
        qrel[t] = s;
    }
    const bool bias_i = (g < 4);

    float sc[NI * 7];
    mx = -3.4e38f;
    #pragma unroll
    for (int i = 0; i < NI; ++i) {
        const int y = h + (I0 + i) - 3;
        #pragma unroll
        for (int j = 0; j < 7; ++j) {
            const int x = w + j - 3;
            float d = dotq(qr, ld16(Kp + CIDX(y, x)));
            d += bias_i ? qrel[I0 + i] : qrel[j];
            sc[i * 7 + j] = d;
            mx = fmaxf(mx, d);
        }
    }
    den = 0.f;
    #pragma unroll
    for (int k = 0; k < NI * 7; ++k) { sc[k] = __expf(sc[k] - mx); den += sc[k]; }
    #pragma unroll
    for (int i = 0; i < NI; ++i) {
        const int y = h + (I0 + i) - 3;
        #pragma unroll
        for (int j = 0; j < 7; ++j) {
            const int x = w + j - 3;
            axpyq(acc, sc[i * 7 + j], ld16(Vp + CIDX(y, x)));
        }
    }
}

__global__ __launch_bounds__(256) void attn_kernel(
    const float* __restrict__ Q,
    const unsigned short* __restrict__ K0,
    const unsigned short* __restrict__ V0,
    const float* __restrict__ rel_h,
    const float* __restrict__ rel_w,
    float* __restrict__ ACC,
    float* __restrict__ Mb,
    float* __restrict__ Db)
{
    const int tid = threadIdx.x;
    const int w   = tid & 63;
    const int h   = blockIdx.x * 4 + (tid >> 6);
    const int g   = blockIdx.y;
    const int z   = blockIdx.z;       // 0..9
    const int pz  = z >> 1;           // part 0..4 (heavy chunk first)
    const int b   = z & 1;

    const size_t slabQ = ((size_t)(b * 8 + g)) << 16;
    const float* qptr = Q + slabQ + (size_t)(h * 64 + w) * 16;

    float qr[16];
    #pragma unroll
    for (int ci = 0; ci < 16; ++ci) qr[ci] = qptr[ci];

    const unsigned short* Kp = K0 + (size_t)(b * 8 + g) * CANVAS_SLAB;
    const unsigned short* Vp = V0 + (size_t)(b * 8 + g) * CANVAS_SLAB;

    float acc[16];
    #pragma unroll
    for (int ci = 0; ci < 16; ++ci) acc[ci] = 0.f;
    float mx, den;

    if (pz == 0) {
        main_chunk<4, 3>(qr, Kp, Vp, rel_h, rel_w, g, h, w, acc, mx, den);
    } else if (pz == 1) {
        main_chunk<0, 2>(qr, Kp, Vp, rel_h, rel_w, g, h, w, acc, mx, den);
    } else if (pz == 2) {
        main_chunk<2, 2>(qr, Kp, Vp, rel_h, rel_w, g, h, w, acc, mx, den);
    } else if (pz == 3) {
        // refine row (w offsets), raw partial
        float sc[15];
        mx = -3.4e38f;
        #pragma unroll
        for (int j = 0; j < 15; ++j) {
            const int x = w + j - 7;
            const float d = dotq(qr, ld16(Kp + CIDX(h, x)));
            sc[j] = d; mx = fmaxf(mx, d);
        }
        den = 0.f;
        #pragma unroll
        for (int j = 0; j < 15; ++j) { sc[j] = __expf(sc[j] - mx); den += sc[j]; }
        #pragma unroll
        for (int j = 0; j < 15; ++j) {
            const int x = w + j - 7;
            axpyq(acc, sc[j], ld16(Vp + CIDX(h, x)));
        }
    } else {
        // refine col (h offsets), raw partial
        float sc[15];
        mx = -3.4e38f;
        #pragma unroll
        for (int i = 0; i < 15; ++i) {
            const int y = h + i - 7;
            const float d = dotq(qr, ld16(Kp + CIDX(y, w)));
            sc[i] = d; mx = fmaxf(mx, d);
        }
        den = 0.f;
        #pragma unroll
        for (int i = 0; i < 15; ++i) { sc[i] = __expf(sc[i] - mx); den += sc[i]; }
        #pragma unroll
        for (int i = 0; i < 15; ++i) {
            const int y = h + i - 7;
            axpyq(acc, sc[i], ld16(Vp + CIDX(y, w)));
        }
    }

    // store raw partials
    const int hw = h * 64 + w;
    float* op = ACC + ((((size_t)(pz * 2 + b)) * 128 + g * 16) << 12) + hw;
    #pragma unroll
    for (int ci = 0; ci < 16; ++ci)
        op[(size_t)ci << 12] = acc[ci];
    const size_t md = ((((size_t)(pz * 2 + b)) * 8 + g) << 12) + hw;
    Mb[md] = mx;
    Db[md] = den;
}
#undef CIDX

// ---------------------------------------------------------------------------
// combine: out = merge(p0,p1,p2) + p3/d3 + p4/d4.  float4 over 1M floats.
// ---------------------------------------------------------------------------
__global__ __launch_bounds__(256) void combine_kernel(
    const float4* __restrict__ ACC,
    const float* __restrict__ Mb, const float* __restrict__ Db,
    float4* __restrict__ out)
{
    const int idx = blockIdx.x * 256 + threadIdx.x;     // 0..262143
    const int i4  = idx & 1023;
    const int ch  = (idx >> 10) & 127;
    const int b   = idx >> 17;
    const int g   = ch >> 4;

    const float4* M4 = (const float4*)Mb;
    const float4* D4 = (const float4*)Db;

    float4 A[5], Mv[3], Dv[5];
    #pragma unroll
    for (int p = 0; p < 5; ++p) {
        A[p]  = ACC[(((size_t)(p * 2 + b) * 128 + ch) << 10) + i4];
        Dv[p] = D4[(((size_t)(p * 2 + b) * 8 + g) << 10) + i4];
    }
    #pragma unroll
    for (int p = 0; p < 3; ++p)
        Mv[p] = M4[(((size_t)(p * 2 + b) * 8 + g) << 10) + i4];

    const float* a0 = (const float*)&A[0]; const float* a1 = (const float*)&A[1];
    const float* a2 = (const float*)&A[2]; const float* a3 = (const float*)&A[3];
    const float* a4 = (const float*)&A[4];
    const float* m0 = (const float*)&Mv[0]; const float* m1 = (const float*)&Mv[1];
    const float* m2 = (const float*)&Mv[2];
    const float* d0 = (const float*)&Dv[0]; const float* d1 = (const float*)&Dv[1];
    const float* d2 = (const float*)&Dv[2]; const float* d3 = (const float*)&Dv[3];
    const float* d4 = (const float*)&Dv[4];

    float res[4];
    #pragma unroll
    for (int c = 0; c < 4; ++c) {
        const float M  = fmaxf(m0[c], fmaxf(m1[c], m2[c]));
        const float e0 = __expf(m0[c] - M);
        const float e1 = __expf(m1[c] - M);
        const float e2 = __expf(m2[c] - M);
        const float num = a0[c] * e0 + a1[c] * e1 + a2[c] * e2;
        const float den = d0[c] * e0 + d1[c] * e1 + d2[c] * e2;
        res[c] = num / den + a3[c] / d3[c] + a4[c] / d4[c];
    }
    out[idx] = make_float4(res[0], res[1], res[2], res[3]);
}

// ---------------------------------------------------------------------------
extern "C" void kernel_launch(void* const* d_in, const int* in_sizes, int n_in,
                              void* d_out, int out_size, void* d_ws, size_t ws_size,
                              hipStream_t stream) {
    (void)in_sizes; (void)n_in; (void)ws_size; (void)out_size;
    const float* fm    = (const float*)d_in[0];
    const float* wq    = (const float*)d_in[1];
    const float* wk    = (const float*)d_in[2];
    const float* wv    = (const float*)d_in[3];
    const float* rel_h = (const float*)d_in[4];
    const float* rel_w = (const float*)d_in[5];

    float* Q = (float*)d_ws;                               // 1048576 f
    unsigned short* K0 = (unsigned short*)(Q + 1048576);   // 1638400 us
    unsigned short* V0 = K0 + 16 * CANVAS_SLAB;            // 1638400 us
    float* ACC = (float*)(V0 + 16 * CANVAS_SLAB);          // 5242880 f
    float* Mb  = ACC + 5242880;                            // 327680 f
    float* Db  = Mb + 327680;                              // 327680 f

    pad_zero_kernel<<<dim3(1600), dim3(256), 0, stream>>>((uint4*)K0);

    conv_kernel<<<dim3(128, 2, 3), dim3(256), 0, stream>>>(
        fm, wq, wk, wv, Q, K0, V0);
    attn_kernel<<<dim3(16, 8, 10), dim3(256), 0, stream>>>(
        Q, K0, V0, rel_h, rel_w, ACC, Mb, Db);
    combine_kernel<<<dim3(1024), dim3(256), 0, stream>>>(
        (const float4*)ACC, Mb, Db, (float4*)d_out);
}

// Round 15
// 102.892 us; speedup vs baseline: 1.5896x; 1.0222x over previous
//
#include <hip/hip_runtime.h>
#include <hip/hip_bf16.h>

__device__ __forceinline__ float bf2f(unsigned short u) {
    union { unsigned int i; float f; } v; v.i = ((unsigned int)u) << 16; return v.f;
}
__device__ __forceinline__ unsigned short f2bf(float f) {
    __hip_bfloat16 h = __float2bfloat16(f);
    return *reinterpret_cast<unsigned short*>(&h);
}

// ws layout:
//   Q    fp32 [b][g][4096][16]                    4 MB
//   K    bf16 canvas [b][g][80][80][16]           3.2768 MB (zero-padded)
//   V    bf16 canvas [b][g][80][80][16]           3.2768 MB
//   ACC  fp32 [p][b][128][4096]  p=0..4           20 MB   raw softmax partials
//   Mb   fp32 [p][b][8][4096]                     1.31 MB chunk max
//   Db   fp32 [p][b][8][4096]                     1.31 MB chunk denom
// v11 = round-9 champion (104.9us) with ONE change: the pad_zero kernel is
// folded into conv (sel=1 blocks zero K pads, sel=2 blocks zero V pads,
// disjoint from interior writes -> no sync needed). One dispatch + one
// launch gap removed.
// Tested-and-regressed levers (do NOT re-apply): fp32 K/V (+28us), per-row
// online softmax (+10), dot chain-split (+13), LDS staging (+9),
// launch_bounds(256,4) (VGPR->64, 204MB scratch spills, +59).

#define CANVAS_SLAB 102400   // 80*80*16 ushorts per (b,g)

// Zero this block's slice of one canvas's pad border.
// 2304 pad cells/slab * 2 uint4 = 4608 uint4-units; 16 blocks/slab -> 288
// units/block; 256 threads -> one unit each + 32 threads do a second.
__device__ __forceinline__ void zero_pad_slice(
    unsigned short* __restrict__ C, int blockId, int tid)
{
    const int slab = blockId >> 4;     // 0..15  (b*8+g)
    const int part = blockId & 15;     // 0..15
    unsigned short* base = C + (size_t)slab * CANVAS_SLAB;
    #pragma unroll
    for (int r = 0; r < 2; ++r) {
        const int t = tid + r * 256;
        if (t < 288) {
            const int u    = part * 288 + t;   // 0..4607
            const int cell = u >> 1;
            const int half = u & 1;
            int row, col;
            if (cell < 640)       { row = cell / 80;  col = cell - row * 80; }
            else if (cell < 1280) { const int c2 = cell - 640;  const int rr = c2 / 80;
                                    row = 72 + rr;  col = c2 - rr * 80; }
            else if (cell < 1792) { const int c2 = cell - 1280;
                                    row = 8 + (c2 >> 3);  col = c2 & 7; }
            else                  { const int c2 = cell - 1792;
                                    row = 8 + (c2 >> 3);  col = 72 + (c2 & 7); }
            *(uint4*)(base + (size_t)(row * 80 + col) * 16 + half * 8) =
                make_uint4(0u, 0u, 0u, 0u);
        }
    }
}

// ---------------------------------------------------------------------------
// conv v3: three 1x1 convs, fp32, register-tiled GEMM; sel=1/2 blocks also
// zero their canvas's pad border (disjoint writes, no barrier needed).
// Block = 64 out-ch x 64 px (thread = 4 ch x 4 px), grid (128,2,3) = 768
// blocks = 3/CU. LDS: w_s + x_s 64x68 each.
// ---------------------------------------------------------------------------
__global__ __launch_bounds__(256) void conv_kernel(
    const float* __restrict__ fm,
    const float* __restrict__ wq, const float* __restrict__ wk,
    const float* __restrict__ wv,
    float* __restrict__ Qout,
    unsigned short* __restrict__ K0,
    unsigned short* __restrict__ V0)
{
    const int sel = blockIdx.z;
    const int by  = blockIdx.y;
    const float* W = (sel == 0) ? wq : ((sel == 1) ? wk : wv);
    const int c0 = (sel == 0) ? 128 : 0;

    __shared__ float w_s[64 * 68];
    __shared__ float x_s[64 * 68];

    const int tid = threadIdx.x;
    const int P0  = blockIdx.x * 64;
    const int b   = P0 >> 12;
    const int hw0 = P0 & 4095;

    // fold pad_zero: K pads by sel=1 blocks, V pads by sel=2 blocks
    if (sel == 1) zero_pad_slice(K0, blockIdx.x * 2 + by, tid);
    else if (sel == 2) zero_pad_slice(V0, blockIdx.x * 2 + by, tid);

    float acc[4][4];
    #pragma unroll
    for (int i = 0; i < 4; ++i)
        #pragma unroll
        for (int j = 0; j < 4; ++j) acc[i][j] = 0.f;

    const int ocb = (tid >> 4) * 4;
    const int pxb = (tid & 15) * 4;

    for (int kh = 0; kh < 128; kh += 64) {
        {
            const int o    = tid >> 2;
            const int koff = (tid & 3) * 16;
            #pragma unroll
            for (int i = 0; i < 4; ++i) {
                float4 v = *(const float4*)(W + (size_t)(by * 64 + o) * 128 + kh + koff + i * 4);
                w_s[(koff + i * 4 + 0) * 68 + o] = v.x;
                w_s[(koff + i * 4 + 1) * 68 + o] = v.y;
                w_s[(koff + i * 4 + 2) * 68 + o] = v.z;
                w_s[(koff + i * 4 + 3) * 68 + o] = v.w;
            }
        }
        {
            const int c  = tid >> 2;
            const int pc = (tid & 3) * 16;
            const float* src = fm + (((size_t)(b * 256 + c0 + kh + c)) << 12) + hw0 + pc;
            #pragma unroll
            for (int i = 0; i < 4; ++i)
                *(float4*)(&x_s[c * 68 + pc + i * 4]) = *(const float4*)(src + i * 4);
        }
        __syncthreads();
        #pragma unroll 8
        for (int k = 0; k < 64; ++k) {
            float4 wa = *(const float4*)(&w_s[k * 68 + ocb]);
            float4 xv = *(const float4*)(&x_s[k * 68 + pxb]);
            const float wf[4] = {wa.x, wa.y, wa.z, wa.w};
            const float xf[4] = {xv.x, xv.y, xv.z, xv.w};
            #pragma unroll
            for (int i = 0; i < 4; ++i)
                #pragma unroll
                for (int j = 0; j < 4; ++j) acc[i][j] += wf[i] * xf[j];
        }
        __syncthreads();
    }

    const int oc  = by * 64 + ocb;
    const int g   = oc >> 4;
    const int lci = oc & 15;
    const int hh  = hw0 >> 6;
    #pragma unroll
    for (int pj = 0; pj < 4; ++pj) {
        const int ww = pxb + pj;
        if (sel == 0) {
            const size_t base = ((((size_t)(b * 8 + g)) << 12) + (hh * 64 + ww)) * 16 + lci;
            *(float4*)(Qout + base) = make_float4(acc[0][pj], acc[1][pj], acc[2][pj], acc[3][pj]);
        } else {
            const size_t cbase = (size_t)(b * 8 + g) * CANVAS_SLAB
                               + ((size_t)((hh + 8) * 80 + (ww + 8))) * 16 + lci;
            unsigned short tmp[4];
            #pragma unroll
            for (int i = 0; i < 4; ++i) tmp[i] = f2bf(acc[i][pj]);
            unsigned short* dst = ((sel == 1) ? K0 : V0) + cbase;
            *(uint2*)dst = *(const uint2*)tmp;
        }
    }
}

// ---------------------------------------------------------------------------
// attn v6 (champion, unchanged): balanced 5-way split with raw partials.
// One thread per (b,g,h,w,part). grid (16, 8, 10), z = part*2 + b.
// ---------------------------------------------------------------------------
struct KV16 { uint4 a, b; };
__device__ __forceinline__ KV16 ld16(const unsigned short* p) {
    KV16 r; r.a = *(const uint4*)p; r.b = *(const uint4*)(p + 8); return r;
}
__device__ __forceinline__ float dotq(const float* q, const KV16& k) {
    const unsigned short* u = (const unsigned short*)&k;
    float s = 0.f;
    #pragma unroll
    for (int c = 0; c < 16; ++c) s += q[c] * bf2f(u[c]);
    return s;
}
__device__ __forceinline__ void axpyq(float* acc, float wgt, const KV16& v) {
    const unsigned short* u = (const unsigned short*)&v;
    #pragma unroll
    for (int c = 0; c < 16; ++c) acc[c] += wgt * bf2f(u[c]);
}

#define CIDX(y, x) (((size_t)(((y) + 8) * 80 + ((x) + 8))) << 4)

// Main-window row-chunk [I0, I0+NI): raw partial (m, den, acc un-normalized).
template<int I0, int NI>
__device__ __forceinline__ void main_chunk(
    const float* qr, const unsigned short* Kp, const unsigned short* Vp,
    const float* __restrict__ rel_h, const float* __restrict__ rel_w,
    int g, int h, int w, float* acc, float& mx, float& den)
{
    float qrel[7];
    const float* rel = (g < 4) ? (rel_h + g * 112) : (rel_w + (g - 4) * 112);
    #pragma unroll
    for (int t = 0; t < 7; ++t) {
        float s = 0.f;
        #pragma unroll
        for (int ci = 0; ci < 16; ++ci) s += qr[ci] * rel[ci * 7 + t];
        qrel[t] = s;
    }
    const bool bias_i = (g < 4);

    float sc[NI * 7];
    mx = -3.4e38f;
    #pragma unroll
    for (int i = 0; i < NI; ++i) {
        const int y = h + (I0 + i) - 3;
        #pragma unroll
        for (int j = 0; j < 7; ++j) {
            const int x = w + j - 3;
            float d = dotq(qr, ld16(Kp + CIDX(y, x)));
            d += bias_i ? qrel[I0 + i] : qrel[j];
            sc[i * 7 + j] = d;
            mx = fmaxf(mx, d);
        }
    }
    den = 0.f;
    #pragma unroll
    for (int k = 0; k < NI * 7; ++k) { sc[k] = __expf(sc[k] - mx); den += sc[k]; }
    #pragma unroll
    for (int i = 0; i < NI; ++i) {
        const int y = h + (I0 + i) - 3;
        #pragma unroll
        for (int j = 0; j < 7; ++j) {
            const int x = w + j - 3;
            axpyq(acc, sc[i * 7 + j], ld16(Vp + CIDX(y, x)));
        }
    }
}

__global__ __launch_bounds__(256) void attn_kernel(
    const float* __restrict__ Q,
    const unsigned short* __restrict__ K0,
    const unsigned short* __restrict__ V0,
    const float* __restrict__ rel_h,
    const float* __restrict__ rel_w,
    float* __restrict__ ACC,
    float* __restrict__ Mb,
    float* __restrict__ Db)
{
    const int tid = threadIdx.x;
    const int w   = tid & 63;
    const int h   = blockIdx.x * 4 + (tid >> 6);
    const int g   = blockIdx.y;
    const int z   = blockIdx.z;       // 0..9
    const int pz  = z >> 1;           // part 0..4 (heavy chunk first)
    const int b   = z & 1;

    const size_t slabQ = ((size_t)(b * 8 + g)) << 16;
    const float* qptr = Q + slabQ + (size_t)(h * 64 + w) * 16;

    float qr[16];
    #pragma unroll
    for (int ci = 0; ci < 16; ++ci) qr[ci] = qptr[ci];

    const unsigned short* Kp = K0 + (size_t)(b * 8 + g) * CANVAS_SLAB;
    const unsigned short* Vp = V0 + (size_t)(b * 8 + g) * CANVAS_SLAB;

    float acc[16];
    #pragma unroll
    for (int ci = 0; ci < 16; ++ci) acc[ci] = 0.f;
    float mx, den;

    if (pz == 0) {
        main_chunk<4, 3>(qr, Kp, Vp, rel_h, rel_w, g, h, w, acc, mx, den);
    } else if (pz == 1) {
        main_chunk<0, 2>(qr, Kp, Vp, rel_h, rel_w, g, h, w, acc, mx, den);
    } else if (pz == 2) {
        main_chunk<2, 2>(qr, Kp, Vp, rel_h, rel_w, g, h, w, acc, mx, den);
    } else if (pz == 3) {
        // refine row (w offsets), raw partial
        float sc[15];
        mx = -3.4e38f;
        #pragma unroll
        for (int j = 0; j < 15; ++j) {
            const int x = w + j - 7;
            const float d = dotq(qr, ld16(Kp + CIDX(h, x)));
            sc[j] = d; mx = fmaxf(mx, d);
        }
        den = 0.f;
        #pragma unroll
        for (int j = 0; j < 15; ++j) { sc[j] = __expf(sc[j] - mx); den += sc[j]; }
        #pragma unroll
        for (int j = 0; j < 15; ++j) {
            const int x = w + j - 7;
            axpyq(acc, sc[j], ld16(Vp + CIDX(h, x)));
        }
    } else {
        // refine col (h offsets), raw partial
        float sc[15];
        mx = -3.4e38f;
        #pragma unroll
        for (int i = 0; i < 15; ++i) {
            const int y = h + i - 7;
            const float d = dotq(qr, ld16(Kp + CIDX(y, w)));
            sc[i] = d; mx = fmaxf(mx, d);
        }
        den = 0.f;
        #pragma unroll
        for (int i = 0; i < 15; ++i) { sc[i] = __expf(sc[i] - mx); den += sc[i]; }
        #pragma unroll
        for (int i = 0; i < 15; ++i) {
            const int y = h + i - 7;
            axpyq(acc, sc[i], ld16(Vp + CIDX(y, w)));
        }
    }

    // store raw partials
    const int hw = h * 64 + w;
    float* op = ACC + ((((size_t)(pz * 2 + b)) * 128 + g * 16) << 12) + hw;
    #pragma unroll
    for (int ci = 0; ci < 16; ++ci)
        op[(size_t)ci << 12] = acc[ci];
    const size_t md = ((((size_t)(pz * 2 + b)) * 8 + g) << 12) + hw;
    Mb[md] = mx;
    Db[md] = den;
}
#undef CIDX

// ---------------------------------------------------------------------------
// combine: out = merge(p0,p1,p2) + p3/d3 + p4/d4.  float4 over 1M floats.
// ---------------------------------------------------------------------------
__global__ __launch_bounds__(256) void combine_kernel(
    const float4* __restrict__ ACC,
    const float* __restrict__ Mb, const float* __restrict__ Db,
    float4* __restrict__ out)
{
    const int idx = blockIdx.x * 256 + threadIdx.x;     // 0..262143
    const int i4  = idx & 1023;
    const int ch  = (idx >> 10) & 127;
    const int b   = idx >> 17;
    const int g   = ch >> 4;

    const float4* M4 = (const float4*)Mb;
    const float4* D4 = (const float4*)Db;

    float4 A[5], Mv[3], Dv[5];
    #pragma unroll
    for (int p = 0; p < 5; ++p) {
        A[p]  = ACC[(((size_t)(p * 2 + b) * 128 + ch) << 10) + i4];
        Dv[p] = D4[(((size_t)(p * 2 + b) * 8 + g) << 10) + i4];
    }
    #pragma unroll
    for (int p = 0; p < 3; ++p)
        Mv[p] = M4[(((size_t)(p * 2 + b) * 8 + g) << 10) + i4];

    const float* a0 = (const float*)&A[0]; const float* a1 = (const float*)&A[1];
    const float* a2 = (const float*)&A[2]; const float* a3 = (const float*)&A[3];
    const float* a4 = (const float*)&A[4];
    const float* m0 = (const float*)&Mv[0]; const float* m1 = (const float*)&Mv[1];
    const float* m2 = (const float*)&Mv[2];
    const float* d0 = (const float*)&Dv[0]; const float* d1 = (const float*)&Dv[1];
    const float* d2 = (const float*)&Dv[2]; const float* d3 = (const float*)&Dv[3];
    const float* d4 = (const float*)&Dv[4];

    float res[4];
    #pragma unroll
    for (int c = 0; c < 4; ++c) {
        const float M  = fmaxf(m0[c], fmaxf(m1[c], m2[c]));
        const float e0 = __expf(m0[c] - M);
        const float e1 = __expf(m1[c] - M);
        const float e2 = __expf(m2[c] - M);
        const float num = a0[c] * e0 + a1[c] * e1 + a2[c] * e2;
        const float den = d0[c] * e0 + d1[c] * e1 + d2[c] * e2;
        res[c] = num / den + a3[c] / d3[c] + a4[c] / d4[c];
    }
    out[idx] = make_float4(res[0], res[1], res[2], res[3]);
}

// ---------------------------------------------------------------------------
extern "C" void kernel_launch(void* const* d_in, const int* in_sizes, int n_in,
                              void* d_out, int out_size, void* d_ws, size_t ws_size,
                              hipStream_t stream) {
    (void)in_sizes; (void)n_in; (void)ws_size; (void)out_size;
    const float* fm    = (const float*)d_in[0];
    const float* wq    = (const float*)d_in[1];
    const float* wk    = (const float*)d_in[2];
    const float* wv    = (const float*)d_in[3];
    const float* rel_h = (const float*)d_in[4];
    const float* rel_w = (const float*)d_in[5];

    float* Q = (float*)d_ws;                               // 1048576 f
    unsigned short* K0 = (unsigned short*)(Q + 1048576);   // 1638400 us
    unsigned short* V0 = K0 + 16 * CANVAS_SLAB;            // 1638400 us
    float* ACC = (float*)(V0 + 16 * CANVAS_SLAB);          // 5242880 f
    float* Mb  = ACC + 5242880;                            // 327680 f
    float* Db  = Mb + 327680;                              // 327680 f

    conv_kernel<<<dim3(128, 2, 3), dim3(256), 0, stream>>>(
        fm, wq, wk, wv, Q, K0, V0);
    attn_kernel<<<dim3(16, 8, 10), dim3(256), 0, stream>>>(
        Q, K0, V0, rel_h, rel_w, ACC, Mb, Db);
    combine_kernel<<<dim3(1024), dim3(256), 0, stream>>>(
        (const float4*)ACC, Mb, Db, (float4*)d_out);
}